// Round 9
// baseline (354.503 us; speedup 1.0000x reference)
//
#include <hip/hip_runtime.h>
#include <cmath>

// Problem constants (from reference)
#define NN  5      // N_NODES
#define BB  4      // batch
#define CCH 256    // channels
#define HWD 1024   // H*W
#define THRESH_V 0.3f
#define EPS_V 1e-12f

// R9: occupancy experiment. All rounds' occupancy data fit "only ~64 KB LDS
// is usable for co-residency": 58KB->1 block, 29KB->2 blocks (occ 17%/28%),
// independent of VGPR. R8 (29KB, KC=16) = 290us with wall ~= 1.8x VALU-busy
// = 2-block barrier serialization. This round: LDS -> 14592 B (KC=8, 8-row
// epilogue bands) so 4 blocks/CU fit under the hypothesis. Compute loop,
// 64-VGPR no-spill budget, ws-pretransposed A staging, XCD swizzle unchanged.

#define CT 64      // channel rows per block
#define WT 64      // hw cols per block
#define KC 8       // k chunk
#define APAD 68    // As/W2s row stride (floats)
#define SPAD 68    // Es row stride (floats) in epilogue

#define W2T_OFF (NN * CCH * CCH)          // second table in ws

// smem layout (floats):
//   staging: Xs[5][8][64] @0 (2560) | As[8][68] @2560 (544) | W2s @3104 (544)
//   epilogue overlay: Es[6][8][68] @0 (3264)
#define XS_FLOATS (NN * KC * WT)          // 2560
#define AS_OFF    XS_FLOATS               // 2560
#define W2S_OFF   (AS_OFF + KC * APAD)    // 3104
#define SMEM_FLOATS (W2S_OFF + KC * APAD) // 3648 floats = 14592 B

// ---------------- prep: transpose conv_w into ws (verified R3) ----------------
// ws: At[i][k][c] = W1[i][c][k] + W2[i][c][k];  W2t[i][k][c] = W2[i][c][k]
__global__ void fub_prep(const float* __restrict__ conv_w, float* __restrict__ ws)
{
    const int t = blockIdx.x * 256 + threadIdx.x;   // 0 .. 5*256*64-1
    if (t >= NN * CCH * 64) return;
    const int c4 = (t & 63) << 2;        // c base 0..252
    const int k  = (t >> 6) & 255;       // 0..255
    const int i  = t >> 14;              // 0..4
    float s1[4], s2[4];
#pragma unroll
    for (int cc = 0; cc < 4; ++cc) {
        const float* p = conv_w + (size_t)(i * CCH + c4 + cc) * (2 * CCH) + k;
        const float w1 = p[0];
        const float w2 = p[CCH];
        s1[cc] = w1 + w2;
        s2[cc] = w2;
    }
    float* At  = ws + (size_t)(i * CCH + k) * CCH + c4;
    float* W2t = ws + W2T_OFF + (size_t)(i * CCH + k) * CCH + c4;
    *(float4*)At  = make_float4(s1[0], s1[1], s1[2], s1[3]);
    *(float4*)W2t = make_float4(s2[0], s2[1], s2[2], s2[3]);
}

// ---------------- main ----------------
__global__ __launch_bounds__(384, 3)
void fub_main(const float* __restrict__ x, const float* __restrict__ wmat,
              const float* __restrict__ ws, const float* __restrict__ conv_b,
              float* __restrict__ out)
{
    __shared__ __align__(16) float smem[SMEM_FLOATS];
    float* Xs  = smem;                 // [5][KC][WT]
    float* As  = smem + AS_OFF;        // [KC][APAD]
    float* W2s = smem + W2S_OFF;       // [KC][APAD]
    float* Es  = smem;                 // [6][8][SPAD] overlay (epilogue only)

    const int tid  = threadIdx.x;
    const int wv   = tid >> 6;        // 0..5 : stream id
    const int lane = tid & 63;

    // XCD-chunked bijective swizzle (1280 % 8 == 0)
    const int wg  = blockIdx.x;
    int L = (wg & 7) * 160 + (wg >> 3);
    const int i   = L % 5;  L /= 5;
    const int ct  = L & 3;  L >>= 2;
    const int b   = L & 3;  L >>= 2;
    const int hwt = L;                 // 0..15

    const int c0  = ct * CT;
    const int hw0 = hwt * WT;

    const int lr = (lane >> 3) << 3;  // frag row base 0,8,...,56
    const int lc = (lane & 7)  << 3;  // frag col base 0,8,...,56

    // stream w<5: A_i @ x[w]; stream 5: W2_i @ x[i]
    const int jx = (wv < NN) ? wv : i;
    const float* Ms = (wv == 5) ? W2s : As;
    const float* Mb = Ms + lr;
    const float* Xb = Xs + jx * (KC * WT) + lc;

    float acc[8][8];
#pragma unroll
    for (int r = 0; r < 8; ++r)
#pragma unroll
        for (int c = 0; c < 8; ++c) acc[r][c] = 0.0f;

    for (int k0 = 0; k0 < CCH; k0 += KC) {
        // ---- stage: 896 float4 total (Xs 640, As 128, W2s 128), 384 thr ----
#pragma unroll
        for (int it = 0; it < 3; ++it) {
            const int t = tid + it * 384;             // 0..1151
            if (t < 640) {
                const int j   = t >> 7;               // 0..4
                const int rem = t & 127;
                const int kk  = rem >> 4;             // 0..7
                const int q4  = (rem & 15) << 2;      // 0..60
                const float4 v = *(const float4*)(
                    x + (size_t)((j * BB + b) * CCH + k0 + kk) * HWD + hw0 + q4);
                *(float4*)(Xs + j * (KC * WT) + kk * WT + q4) = v;
            } else if (t < 896) {
                const int u   = t - 640;              // 0..255
                const int tbl = u >> 7;               // 0=A, 1=W2
                const int rem = u & 127;
                const int kk  = rem >> 4;             // 0..7
                const int c4  = (rem & 15) << 2;      // 0..60
                const float4 v = *(const float4*)(
                    ws + (size_t)(tbl ? W2T_OFF : 0)
                       + (size_t)(i * CCH + k0 + kk) * CCH + c0 + c4);
                *(float4*)((tbl ? W2s : As) + kk * APAD + c4) = v;
            }
        }
        __syncthreads();

        // ---- compute: both operands from LDS, 8x8 frag/lane ----
#pragma unroll
        for (int kk = 0; kk < KC; ++kk) {
            const float4 a0 = *(const float4*)(Mb + kk * APAD);
            const float4 a1 = *(const float4*)(Mb + kk * APAD + 4);
            const float4 x0 = *(const float4*)(Xb + kk * WT);
            const float4 x1 = *(const float4*)(Xb + kk * WT + 4);
            const float ar[8] = {a0.x, a0.y, a0.z, a0.w, a1.x, a1.y, a1.z, a1.w};
            const float xc[8] = {x0.x, x0.y, x0.z, x0.w, x1.x, x1.y, x1.z, x1.w};
#pragma unroll
            for (int r = 0; r < 8; ++r)
#pragma unroll
                for (int c = 0; c < 8; ++c)
                    acc[r][c] = fmaf(ar[r], xc[c], acc[r][c]);
        }
        __syncthreads();
    }

    // ---- epilogue: 8 passes over 8-row bands; exchange streams via LDS ----
    float wrow[NN];
#pragma unroll
    for (int j = 0; j < NN; ++j) wrow[j] = wmat[i * NN + j];

    const int g = lane >> 3;          // frag row-group 0..7 (lr = 8g)

#pragma unroll
    for (int rh = 0; rh < 8; ++rh) {
        if (g == rh) {
            float* Eb = Es + wv * (KC * SPAD) + lc;   // 8 rows per band
#pragma unroll
            for (int r = 0; r < 8; ++r) {
                *(float4*)(Eb + r * SPAD) =
                    make_float4(acc[r][0], acc[r][1], acc[r][2], acc[r][3]);
                *(float4*)(Eb + r * SPAD + 4) =
                    make_float4(acc[r][4], acc[r][5], acc[r][6], acc[r][7]);
            }
        }
        __syncthreads();

        if (tid < 256) {
            const int row  = tid >> 5;           // 0..7
            const int col2 = (tid & 31) << 1;    // 0..62 step 2
            const int c    = c0 + rh * 8 + row;
            const float bias = conv_b[i * CCH + c];

            const float2 T = *(const float2*)(Es + 5 * (KC * SPAD) + row * SPAD + col2);
            const float Tv[2] = {T.x, T.y};

            float num[2] = {0.f, 0.f};
            float sq [2] = {0.f, 0.f};
#pragma unroll
            for (int j = 0; j < NN; ++j) {
                const float2 s  = *(const float2*)(Es + j * (KC * SPAD) + row * SPAD + col2);
                const float2 xj = *(const float2*)(
                    x + (size_t)((j * BB + b) * CCH + c) * HWD + hw0 + col2);
                const float sv[2] = {s.x, s.y};
                const float xv[2] = {xj.x, xj.y};
#pragma unroll
                for (int cc = 0; cc < 2; ++cc) {
                    const float target = sv[cc] + Tv[cc] + bias;
                    const float dist   = xv[cc] - target;
                    const float z      = dist * wrow[j];
                    float e = 1.0f / (1.0f + expf(-z));
                    e = (e > THRESH_V) ? e : 0.0f;
                    sq[cc]  = fmaf(e, e, sq[cc]);
                    num[cc] = fmaf(e, xv[cc], num[cc]);
                }
            }
            float2 res;
            res.x = num[0] / fmaxf(sqrtf(sq[0]), EPS_V);
            res.y = num[1] / fmaxf(sqrtf(sq[1]), EPS_V);
            *(float2*)(out + (size_t)((i * BB + b) * CCH + c) * HWD + hw0 + col2) = res;
        }
        __syncthreads();
    }
}

extern "C" void kernel_launch(void* const* d_in, const int* in_sizes, int n_in,
                              void* d_out, int out_size, void* d_ws, size_t ws_size,
                              hipStream_t stream) {
    const float* x      = (const float*)d_in[0];
    const float* w      = (const float*)d_in[1];
    const float* conv_w = (const float*)d_in[2];
    const float* conv_b = (const float*)d_in[3];
    float* out = (float*)d_out;
    float* ws  = (float*)d_ws;   // needs 2*5*256*256*4 B = 2.62 MB

    // prep: 5*256*64 = 81920 work items
    fub_prep<<<dim3(320), dim3(256), 0, stream>>>(conv_w, ws);

    // grid: hwt(16) * b(4) * ct(4) * i(5) = 1280 blocks of 384 threads
    fub_main<<<dim3(1280), dim3(384), 0, stream>>>(x, w, ws, conv_b, out);
}